// Round 10
// baseline (919.100 us; speedup 1.0000x reference)
//
#include <hip/hip_runtime.h>
#include <hip/hip_bf16.h>

// GCN 2-layer, fp32 I/O. Pipeline per layer:
//   gemm1 (W-in-registers, wave-per-node, no LDS) -> bin_count -> scan_small
//        -> bin_scatter (LDS counting sort by dst>>8) -> bucket_sort (by dst&255 -> rowptr)
//        -> gather (wave-per-node, 4 edges per gather instr via lane-quartering)
// h1 kept bf16. Record int2: .x = src | (dst&255)<<20, .y = w bits.

#define EPB 4096     // edges per binning block
#define NBMAX 512    // max buckets (N <= 131072)
#define CAP 6144     // max records per bucket (avg 4096; 32-sigma headroom)

// ---------------- gemm1: [N,128] @ [128,64] -> bf16 [N,64] ----------------
// One wave per node (grid-stride). W1 column for this lane's feat lives in 128 VGPRs.
// x row read via wave-uniform scalar loads. 4 independent FMA chains.
__global__ __launch_bounds__(256, 3) void gemm1_kernel(const float* __restrict__ x,
                                                       const float* __restrict__ W1,
                                                       __hip_bfloat16* __restrict__ h1,
                                                       int n_nodes, int total_waves) {
    int lane = threadIdx.x & 63;
    int wid = __builtin_amdgcn_readfirstlane(threadIdx.x >> 6);  // force wave-uniform
    int wave = blockIdx.x * 4 + wid;

    float w[128];
#pragma unroll
    for (int k = 0; k < 128; ++k) w[k] = W1[k * 64 + lane];   // coalesced, L2-hot

    for (int n = wave; n < n_nodes; n += total_waves) {
        const float* xp = x + (size_t)n * 128;                // uniform base -> s_load
        float a0 = 0.f, a1 = 0.f, a2 = 0.f, a3 = 0.f;
#pragma unroll
        for (int k = 0; k < 128; k += 4) {
            a0 = fmaf(xp[k + 0], w[k + 0], a0);
            a1 = fmaf(xp[k + 1], w[k + 1], a1);
            a2 = fmaf(xp[k + 2], w[k + 2], a2);
            a3 = fmaf(xp[k + 3], w[k + 3], a3);
        }
        h1[(size_t)n * 64 + lane] = __float2bfloat16((a0 + a1) + (a2 + a3));
    }
}

// ---------------- gemm2: [N,64] @ [64,16] -> fp32 [N,16] (256-thr LDS tile) ----------------
__global__ __launch_bounds__(256) void gemm2_kernel(const float* __restrict__ agg1,
                                                    const float* __restrict__ W2,
                                                    float* __restrict__ h2, int n_nodes) {
    __shared__ float As[32][132];
    __shared__ float Bs[32][16];
    int tid = threadIdx.x;
    int node0 = blockIdx.x * 128;
    int n2 = (tid & 63) * 2;
    int f4 = (tid >> 6) * 4;
    float acc[2][4];
#pragma unroll
    for (int i = 0; i < 2; ++i)
#pragma unroll
        for (int j = 0; j < 4; ++j) acc[i][j] = 0.f;

    const float4* a4 = reinterpret_cast<const float4*>(agg1);
    const float4* W4 = reinterpret_cast<const float4*>(W2);

    for (int s = 0; s < 2; ++s) {
#pragma unroll
        for (int j = 0; j < 4; ++j) {
            int idx = tid + j * 256;
            int n = idx >> 3;
            int kq = idx & 7;
            float4 v = make_float4(0.f, 0.f, 0.f, 0.f);
            if (node0 + n < n_nodes) v = a4[(size_t)(node0 + n) * 16 + s * 8 + kq];
            int k4 = kq * 4;
            As[k4 + 0][n] = v.x;
            As[k4 + 1][n] = v.y;
            As[k4 + 2][n] = v.z;
            As[k4 + 3][n] = v.w;
        }
        if (tid < 128) {
            int k = tid >> 2, fq = tid & 3;
            *reinterpret_cast<float4*>(&Bs[k][fq * 4]) = W4[(size_t)(s * 32 + k) * 4 + fq];
        }
        __syncthreads();
#pragma unroll
        for (int kk = 0; kk < 32; ++kk) {
            float2 a = *reinterpret_cast<const float2*>(&As[kk][n2]);
            float4 b = *reinterpret_cast<const float4*>(&Bs[kk][f4]);
            float av[2] = {a.x, a.y};
            float bv[4] = {b.x, b.y, b.z, b.w};
#pragma unroll
            for (int i = 0; i < 2; ++i)
#pragma unroll
                for (int j = 0; j < 4; ++j) acc[i][j] += av[i] * bv[j];
        }
        __syncthreads();
    }
#pragma unroll
    for (int i = 0; i < 2; ++i) {
        int n = node0 + n2 + i;
        if (n < n_nodes)
            *reinterpret_cast<float4*>(h2 + (size_t)n * 16 + f4) =
                make_float4(acc[i][0], acc[i][1], acc[i][2], acc[i][3]);
    }
}

// ---------------- binning: per-block hist + bucket totals -> base/cursor -> runs ----------------

__global__ void bin_count_kernel(const int* __restrict__ ei, int* __restrict__ hist_g,
                                 int* __restrict__ bucket_total, int n_edges, int nb) {
    __shared__ int hist[NBMAX];
    int tid = threadIdx.x, blk = blockIdx.x;
    for (int i = tid; i < nb; i += 256) hist[i] = 0;
    __syncthreads();
    int e0 = blk * EPB;
#pragma unroll
    for (int j = 0; j < EPB / 256; ++j) {
        int e = e0 + tid + j * 256;
        if (e < n_edges) atomicAdd(&hist[ei[n_edges + e] >> 8], 1);
    }
    __syncthreads();
    for (int i = tid; i < nb; i += 256) {
        int h = hist[i];
        hist_g[blk * nb + i] = h;
        if (h > 0) atomicAdd(&bucket_total[i], h);
    }
}

__global__ __launch_bounds__(512) void scan_small_kernel(const int* __restrict__ bucket_total,
                                                         int* __restrict__ bucket_base,
                                                         int* __restrict__ cursor, int nb) {
    __shared__ int tmp[512];
    int tid = threadIdx.x;
    int v = (tid < nb) ? bucket_total[tid] : 0;
    tmp[tid] = v;
    __syncthreads();
    for (int off = 1; off < 512; off <<= 1) {
        int t = (tid >= off) ? tmp[tid - off] : 0;
        __syncthreads();
        tmp[tid] += t;
        __syncthreads();
    }
    if (tid < nb) {
        int excl = tmp[tid] - v;
        bucket_base[tid] = excl;
        cursor[tid] = excl;
    }
    if (tid == 0) bucket_base[nb] = tmp[511];
}

__global__ void bin_scatter_kernel(const int* __restrict__ ei, const float* __restrict__ ew,
                                   const int* __restrict__ hist_g, int* __restrict__ cursor,
                                   int2* __restrict__ rec_out, int n_edges, int nb) {
    __shared__ int2 srec[EPB];               // 32 KB
    __shared__ unsigned short sbkt[EPB];     // 8 KB
    __shared__ int loff[NBMAX], cur[NBMAX], gbase[NBMAX];
    __shared__ int p[256];
    int tid = threadIdx.x, blk = blockIdx.x;
    int e0 = blk * EPB;
    int cnt = min(EPB, n_edges - e0);
    for (int i = tid; i < nb; i += 256) loff[i] = hist_g[blk * nb + i];
    __syncthreads();
    int b0 = tid * 2;
    int c0 = (b0 < nb) ? loff[b0] : 0;
    int c1 = (b0 + 1 < nb) ? loff[b0 + 1] : 0;
    p[tid] = c0 + c1;
    __syncthreads();
    for (int off = 1; off < 256; off <<= 1) {
        int t = (tid >= off) ? p[tid - off] : 0;
        __syncthreads();
        p[tid] += t;
        __syncthreads();
    }
    int base = (tid > 0) ? p[tid - 1] : 0;
    __syncthreads();
    if (b0 < nb)     { loff[b0] = base;          cur[b0] = base; }
    if (b0 + 1 < nb) { loff[b0 + 1] = base + c0; cur[b0 + 1] = base + c0; }
    if (b0 < nb)     gbase[b0]     = (c0 > 0) ? atomicAdd(&cursor[b0], c0) : 0;
    if (b0 + 1 < nb) gbase[b0 + 1] = (c1 > 0) ? atomicAdd(&cursor[b0 + 1], c1) : 0;
    __syncthreads();
#pragma unroll
    for (int j = 0; j < EPB / 256; ++j) {
        int e = e0 + tid + j * 256;
        if (e < n_edges) {
            int s = ei[e], d = ei[n_edges + e];
            int b = d >> 8;
            int r = atomicAdd(&cur[b], 1);
            srec[r] = make_int2(s | ((d & 255) << 20), __float_as_int(ew[e]));
            sbkt[r] = (unsigned short)b;
        }
    }
    __syncthreads();
    for (int i = tid; i < cnt; i += 256) {
        int b = sbkt[i];
        rec_out[gbase[b] + (i - loff[b])] = srec[i];
    }
}

// ---------------- per-bucket node sort (-> dst-sorted recs + rowptr) ----------------

__global__ __launch_bounds__(256) void bucket_sort_kernel(
        const int2* __restrict__ rec_in, const int* __restrict__ bucket_base,
        int2* __restrict__ rec_out, int* __restrict__ rowptr,
        int n_nodes, int n_edges, int nb) {
    __shared__ int2 srec[CAP];               // 48 KB
    __shared__ int hist[256], cur[256], rp[256];
    int tid = threadIdx.x, b = blockIdx.x;
    int start = bucket_base[b];
    int end = bucket_base[b + 1];
    int cnt = end - start;
    hist[tid] = 0;
    __syncthreads();
    for (int i = tid; i < cnt; i += 256) {
        int2 r = rec_in[start + i];
        atomicAdd(&hist[(r.x >> 20) & 255], 1);
    }
    __syncthreads();
    int v = hist[tid];
    rp[tid] = v;
    __syncthreads();
    for (int off = 1; off < 256; off <<= 1) {
        int t = (tid >= off) ? rp[tid - off] : 0;
        __syncthreads();
        rp[tid] += t;
        __syncthreads();
    }
    int excl = rp[tid] - v;
    cur[tid] = excl;
    int node = (b << 8) + tid;
    if (node < n_nodes) rowptr[node] = start + excl;
    if (b == nb - 1 && tid == 0) rowptr[n_nodes] = n_edges;
    __syncthreads();
    for (int i = tid; i < cnt; i += 256) {
        int2 r = rec_in[start + i];
        int rk = atomicAdd(&cur[(r.x >> 20) & 255], 1);
        if (rk < CAP) srec[rk] = r;
    }
    __syncthreads();
    int lim = min(cnt, CAP);
    for (int i = tid; i < lim; i += 256) rec_out[start + i] = srec[i];
}

// ---------------- gather1: wave per node, 4 edges per gather instruction ----------------
// Lane = (quarter q, uint2-index fl): lane covers feats 4fl..4fl+3 (bf16 pairs),
// quarter q processes edge i+q. One 64-lane uint2 load = 4 edges x 128 B rows.
__global__ void gather1_kernel(const __hip_bfloat16* __restrict__ h1,
                               const int* __restrict__ rowptr,
                               const int2* __restrict__ rec,
                               float* __restrict__ agg, int n_nodes) {
    int n = blockIdx.x * 4 + (threadIdx.x >> 6);
    if (n >= n_nodes) return;
    int lane = threadIdx.x & 63;
    int q = lane >> 4;
    int fl = lane & 15;
    const uint2* h1v = reinterpret_cast<const uint2*>(h1);
    int i = rowptr[n], end = rowptr[n + 1];
    float a0 = 0.f, a1 = 0.f, a2 = 0.f, a3 = 0.f;
    for (; i + 7 < end; i += 8) {           // 8 edges: 2 rec loads + 2 gathers
        int2 r0 = rec[i + q];
        int2 r1 = rec[i + 4 + q];
        uint2 v0 = h1v[(size_t)(r0.x & 0xFFFFF) * 16 + fl];
        uint2 v1 = h1v[(size_t)(r1.x & 0xFFFFF) * 16 + fl];
        float w0 = __int_as_float(r0.y), w1 = __int_as_float(r1.y);
        a0 += __uint_as_float(v0.x << 16) * w0;
        a1 += __uint_as_float(v0.x & 0xFFFF0000u) * w0;
        a2 += __uint_as_float(v0.y << 16) * w0;
        a3 += __uint_as_float(v0.y & 0xFFFF0000u) * w0;
        a0 += __uint_as_float(v1.x << 16) * w1;
        a1 += __uint_as_float(v1.x & 0xFFFF0000u) * w1;
        a2 += __uint_as_float(v1.y << 16) * w1;
        a3 += __uint_as_float(v1.y & 0xFFFF0000u) * w1;
    }
    if (i + 3 < end) {                      // 4 edges
        int2 r = rec[i + q];
        uint2 v = h1v[(size_t)(r.x & 0xFFFFF) * 16 + fl];
        float w = __int_as_float(r.y);
        a0 += __uint_as_float(v.x << 16) * w;
        a1 += __uint_as_float(v.x & 0xFFFF0000u) * w;
        a2 += __uint_as_float(v.y << 16) * w;
        a3 += __uint_as_float(v.y & 0xFFFF0000u) * w;
        i += 4;
    }
    if (i + q < end) {                      // ragged tail (quarter-masked)
        int2 r = rec[i + q];
        uint2 v = h1v[(size_t)(r.x & 0xFFFFF) * 16 + fl];
        float w = __int_as_float(r.y);
        a0 += __uint_as_float(v.x << 16) * w;
        a1 += __uint_as_float(v.x & 0xFFFF0000u) * w;
        a2 += __uint_as_float(v.y << 16) * w;
        a3 += __uint_as_float(v.y & 0xFFFF0000u) * w;
    }
    // reduce across quarters (lanes l, l^16, l^32, l^48 hold the same feats)
    a0 += __shfl_xor(a0, 16, 64);  a0 += __shfl_xor(a0, 32, 64);
    a1 += __shfl_xor(a1, 16, 64);  a1 += __shfl_xor(a1, 32, 64);
    a2 += __shfl_xor(a2, 16, 64);  a2 += __shfl_xor(a2, 32, 64);
    a3 += __shfl_xor(a3, 16, 64);  a3 += __shfl_xor(a3, 32, 64);
    if (q == 0) {
        float4 st = make_float4(fmaxf(a0, 0.f), fmaxf(a1, 0.f),
                                fmaxf(a2, 0.f), fmaxf(a3, 0.f));   // fused relu
        *reinterpret_cast<float4*>(&agg[(size_t)n * 64 + fl * 4]) = st;
    }
}

// ---------------- gather2: wave per node, 4 edges per gather instruction ----------------
__global__ void gather2_kernel(const float* __restrict__ h2,
                               const int* __restrict__ rowptr,
                               const int2* __restrict__ rec,
                               float* __restrict__ out, int n_nodes) {
    int n = blockIdx.x * 4 + (threadIdx.x >> 6);
    if (n >= n_nodes) return;
    int lane = threadIdx.x & 63;
    int q = lane >> 4;
    int fl = lane & 15;
    int i = rowptr[n], end = rowptr[n + 1];
    float a0 = 0.f, a1 = 0.f;
    for (; i + 7 < end; i += 8) {
        int2 r0 = rec[i + q];
        int2 r1 = rec[i + 4 + q];
        float v0 = h2[(size_t)(r0.x & 0xFFFFF) * 16 + fl];
        float v1 = h2[(size_t)(r1.x & 0xFFFFF) * 16 + fl];
        a0 += v0 * __int_as_float(r0.y);
        a1 += v1 * __int_as_float(r1.y);
    }
    if (i + 3 < end) {
        int2 r = rec[i + q];
        a0 += h2[(size_t)(r.x & 0xFFFFF) * 16 + fl] * __int_as_float(r.y);
        i += 4;
    }
    if (i + q < end) {
        int2 r = rec[i + q];
        a1 += h2[(size_t)(r.x & 0xFFFFF) * 16 + fl] * __int_as_float(r.y);
    }
    float a = a0 + a1;
    a += __shfl_xor(a, 16, 64);
    a += __shfl_xor(a, 32, 64);
    if (q == 0) out[(size_t)n * 16 + fl] = a;
}

// ---------------- launch ----------------

extern "C" void kernel_launch(void* const* d_in, const int* in_sizes, int n_in,
                              void* d_out, int out_size, void* d_ws, size_t ws_size,
                              hipStream_t stream) {
    const float* x   = (const float*)d_in[0];
    const int*   ei1 = (const int*)d_in[1];
    const int*   ei2 = (const int*)d_in[2];
    const float* ew1 = (const float*)d_in[3];
    const float* ew2 = (const float*)d_in[4];
    const float* W1  = (const float*)d_in[5];
    const float* W2  = (const float*)d_in[6];

    const int n_nodes = in_sizes[0] / 128;          // 100000
    const int n_edges = in_sizes[1] / 2;            // 1600000
    const int nb   = (n_nodes + 255) >> 8;          // 391 buckets
    const int nblk = (n_edges + EPB - 1) / EPB;     // 391 binning blocks

    // ws layout (4-byte units)
    __hip_bfloat16* h1 = (__hip_bfloat16*)d_ws;          // N*64 bf16
    float* agg1   = (float*)d_ws + (size_t)n_nodes * 32; // N*64
    float* h2     = agg1 + (size_t)n_nodes * 64;         // N*16
    int2*  recbuf = (int2*)(h2 + (size_t)n_nodes * 16);  // E int2 (bucket-sorted)
    int2*  rec2   = recbuf + n_edges;                    // E int2 (node-sorted)
    int*   hist_g = (int*)(rec2 + n_edges);              // nblk*nb (block-major)
    int*   btotal = hist_g + nblk * nb;                  // nb
    int*   bbase  = btotal + nb;                         // nb+1
    int*   cursor = bbase + nb + 1;                      // nb
    int*   rowptr = cursor + nb;                         // N+1
    float* out    = (float*)d_out;

    const int g1_blocks = 1024;                          // 4096 waves, grid-stride
    // ---- layer 1 ----
    gemm1_kernel<<<g1_blocks, 256, 0, stream>>>(x, W1, h1, n_nodes, g1_blocks * 4);
    hipMemsetAsync(btotal, 0, nb * sizeof(int), stream);
    bin_count_kernel<<<nblk, 256, 0, stream>>>(ei1, hist_g, btotal, n_edges, nb);
    scan_small_kernel<<<1, 512, 0, stream>>>(btotal, bbase, cursor, nb);
    bin_scatter_kernel<<<nblk, 256, 0, stream>>>(ei1, ew1, hist_g, cursor, recbuf, n_edges, nb);
    bucket_sort_kernel<<<nb, 256, 0, stream>>>(recbuf, bbase, rec2, rowptr,
                                               n_nodes, n_edges, nb);
    gather1_kernel<<<(n_nodes + 3) / 4, 256, 0, stream>>>(h1, rowptr, rec2, agg1, n_nodes);

    // ---- layer 2 ----
    gemm2_kernel<<<(n_nodes + 127) / 128, 256, 0, stream>>>(agg1, W2, h2, n_nodes);
    hipMemsetAsync(btotal, 0, nb * sizeof(int), stream);
    bin_count_kernel<<<nblk, 256, 0, stream>>>(ei2, hist_g, btotal, n_edges, nb);
    scan_small_kernel<<<1, 512, 0, stream>>>(btotal, bbase, cursor, nb);
    bin_scatter_kernel<<<nblk, 256, 0, stream>>>(ei2, ew2, hist_g, cursor, recbuf, n_edges, nb);
    bucket_sort_kernel<<<nb, 256, 0, stream>>>(recbuf, bbase, rec2, rowptr,
                                               n_nodes, n_edges, nb);
    gather2_kernel<<<(n_nodes + 3) / 4, 256, 0, stream>>>(h2, rowptr, rec2, out, n_nodes);
}

// Round 11
// 516.469 us; speedup vs baseline: 1.7796x; 1.7796x over previous
//
#include <hip/hip_runtime.h>
#include <hip/hip_bf16.h>

// GCN 2-layer, fp32 I/O. Pipeline per layer (5 kernels):
//   gemm (W-in-VGPRs, wave-per-node) -> init_cursor -> bin_scatter (LDS counting sort by
//   dst>>8 into fixed-stride bucket regions, atomic run reservation) -> bucket_sort
//   (in-LDS sort by dst&255 -> rowrange int2) -> gather (4 edges/instr lane-quartering)
// h1 bf16. Record int2: .x = src | (dst&255)<<20, .y = w bits. Bucket stride 5120 (16-sigma).

#define EPB 4096      // edges per binning block
#define NBMAX 512     // max buckets (N <= 131072)
#define BSTRIDE 5120  // fixed records per bucket region (avg 4096 + 16 sigma)

// ---------------- gemm1: [N,128] @ [128,64] -> bf16 [N,64] ----------------
// One wave per node (grid-stride). Lane = out-feat; W1 column in 128 VGPRs.
// x row is wave-uniform -> scalar loads. NOTE: launch_bounds min-waves=2 (256 VGPR cap)
// -- (256,3) capped at 85 VGPR and spilled w[128] to scratch (R10: 590us, FETCH 642MB).
__global__ __launch_bounds__(256, 2) void gemm1_kernel(const float* __restrict__ x,
                                                       const float* __restrict__ W1,
                                                       __hip_bfloat16* __restrict__ h1,
                                                       int n_nodes, int total_waves) {
    int lane = threadIdx.x & 63;
    int wid = __builtin_amdgcn_readfirstlane(threadIdx.x >> 6);  // wave-uniform
    int wave = blockIdx.x * 4 + wid;

    float w[128];
#pragma unroll
    for (int k = 0; k < 128; ++k) w[k] = W1[k * 64 + lane];   // coalesced, L2-hot

    for (int n = wave; n < n_nodes; n += total_waves) {
        const float* xp = x + (size_t)n * 128;                // uniform base -> s_load
        float a0 = 0.f, a1 = 0.f, a2 = 0.f, a3 = 0.f;
#pragma unroll
        for (int k = 0; k < 128; k += 4) {
            a0 = fmaf(xp[k + 0], w[k + 0], a0);
            a1 = fmaf(xp[k + 1], w[k + 1], a1);
            a2 = fmaf(xp[k + 2], w[k + 2], a2);
            a3 = fmaf(xp[k + 3], w[k + 3], a3);
        }
        h1[(size_t)n * 64 + lane] = __float2bfloat16((a0 + a1) + (a2 + a3));
    }
}

// ---------------- gemm2: [N,64] @ [64,16] -> fp32 [N,16] ----------------
// Quarter-wave per node: lane = (node_sub q, feat f). W2 column in 64 VGPRs.
__global__ __launch_bounds__(256, 4) void gemm2_kernel(const float* __restrict__ agg1,
                                                       const float* __restrict__ W2,
                                                       float* __restrict__ h2,
                                                       int n_nodes, int total_waves) {
    int lane = threadIdx.x & 63;
    int q = lane >> 4;
    int f = lane & 15;
    int wave = blockIdx.x * 4 + (threadIdx.x >> 6);

    float w[64];
#pragma unroll
    for (int k = 0; k < 64; ++k) w[k] = W2[k * 16 + f];

    for (int base = wave * 4; base < n_nodes; base += total_waves * 4) {
        int n = base + q;
        int nc = (n < n_nodes) ? n : (n_nodes - 1);
        const float4* ap = reinterpret_cast<const float4*>(agg1 + (size_t)nc * 64);
        float a0 = 0.f, a1 = 0.f, a2 = 0.f, a3 = 0.f;
#pragma unroll
        for (int k4 = 0; k4 < 16; ++k4) {
            float4 v = ap[k4];
            a0 = fmaf(v.x, w[k4 * 4 + 0], a0);
            a1 = fmaf(v.y, w[k4 * 4 + 1], a1);
            a2 = fmaf(v.z, w[k4 * 4 + 2], a2);
            a3 = fmaf(v.w, w[k4 * 4 + 3], a3);
        }
        if (n < n_nodes) h2[(size_t)n * 16 + f] = (a0 + a1) + (a2 + a3);
    }
}

// ---------------- init: cursor[b] = b * BSTRIDE ----------------
__global__ __launch_bounds__(512) void init_cursor_kernel(int* __restrict__ cursor, int nb) {
    int i = threadIdx.x;
    if (i < nb) cursor[i] = i * BSTRIDE;
}

// ---------------- bin_scatter: LDS counting sort by dst>>8, atomic run reservation ----------------
__global__ void bin_scatter_kernel(const int* __restrict__ ei, const float* __restrict__ ew,
                                   int* __restrict__ cursor, int2* __restrict__ rec_out,
                                   int n_edges, int nb) {
    __shared__ int2 srec[EPB];               // 32 KB
    __shared__ unsigned short sbkt[EPB];     // 8 KB
    __shared__ int hist[NBMAX], loff[NBMAX], cur[NBMAX], gbase[NBMAX];  // 8 KB
    __shared__ int p[256];
    int tid = threadIdx.x, blk = blockIdx.x;
    int e0 = blk * EPB;
    int cnt = min(EPB, n_edges - e0);
    for (int i = tid; i < nb; i += 256) hist[i] = 0;
    __syncthreads();
#pragma unroll
    for (int j = 0; j < EPB / 256; ++j) {
        int e = e0 + tid + j * 256;
        if (e < n_edges) atomicAdd(&hist[ei[n_edges + e] >> 8], 1);
    }
    __syncthreads();
    // exclusive scan of hist -> loff (2 buckets/thread + Hillis-Steele over partials)
    int b0 = tid * 2;
    int c0 = (b0 < nb) ? hist[b0] : 0;
    int c1 = (b0 + 1 < nb) ? hist[b0 + 1] : 0;
    p[tid] = c0 + c1;
    __syncthreads();
    for (int off = 1; off < 256; off <<= 1) {
        int t = (tid >= off) ? p[tid - off] : 0;
        __syncthreads();
        p[tid] += t;
        __syncthreads();
    }
    int base = (tid > 0) ? p[tid - 1] : 0;
    __syncthreads();
    if (b0 < nb)     { loff[b0] = base;          cur[b0] = base; }
    if (b0 + 1 < nb) { loff[b0 + 1] = base + c0; cur[b0 + 1] = base + c0; }
    // reserve run space in this bucket's fixed region (inter-block order nondeterministic)
    if (b0 < nb)     gbase[b0]     = (c0 > 0) ? atomicAdd(&cursor[b0], c0) : 0;
    if (b0 + 1 < nb) gbase[b0 + 1] = (c1 > 0) ? atomicAdd(&cursor[b0 + 1], c1) : 0;
    __syncthreads();
    // rank + stage (LDS counting sort by bucket)
#pragma unroll
    for (int j = 0; j < EPB / 256; ++j) {
        int e = e0 + tid + j * 256;
        if (e < n_edges) {
            int s = ei[e], d = ei[n_edges + e];
            int b = d >> 8;
            int r = atomicAdd(&cur[b], 1);
            srec[r] = make_int2(s | ((d & 255) << 20), __float_as_int(ew[e]));
            sbkt[r] = (unsigned short)b;
        }
    }
    __syncthreads();
    // coalesced run writes
    for (int i = tid; i < cnt; i += 256) {
        int b = sbkt[i];
        rec_out[gbase[b] + (i - loff[b])] = srec[i];
    }
}

// ---------------- bucket_sort: in-LDS sort by dst&255 -> rowrange ----------------
__global__ __launch_bounds__(256) void bucket_sort_kernel(
        const int2* __restrict__ rec_in, const int* __restrict__ cursor,
        int2* __restrict__ rec_out, int2* __restrict__ rowrange, int n_nodes, int nb) {
    __shared__ int2 srec[BSTRIDE];           // 40 KB
    __shared__ int hist[256], cur[256], rp[256];
    int tid = threadIdx.x, b = blockIdx.x;
    int start = b * BSTRIDE;
    int cnt = min(cursor[b] - start, BSTRIDE);   // cursor now holds base+count
    hist[tid] = 0;
    __syncthreads();
    for (int i = tid; i < cnt; i += 256) {
        int2 r = rec_in[start + i];
        atomicAdd(&hist[(r.x >> 20) & 255], 1);
    }
    __syncthreads();
    int v = hist[tid];
    rp[tid] = v;
    __syncthreads();
    for (int off = 1; off < 256; off <<= 1) {
        int t = (tid >= off) ? rp[tid - off] : 0;
        __syncthreads();
        rp[tid] += t;
        __syncthreads();
    }
    int excl = rp[tid] - v;
    cur[tid] = excl;
    int node = (b << 8) + tid;
    if (node < n_nodes) rowrange[node] = make_int2(start + excl, start + excl + v);
    __syncthreads();
    for (int i = tid; i < cnt; i += 256) {
        int2 r = rec_in[start + i];
        int rk = atomicAdd(&cur[(r.x >> 20) & 255], 1);
        if (rk < BSTRIDE) srec[rk] = r;
    }
    __syncthreads();
    for (int i = tid; i < cnt; i += 256) rec_out[start + i] = srec[i];
}

// ---------------- gather1: wave per node, 4 edges per gather instruction ----------------
// Lane = (quarter q, uint2-index fl): lane covers feats 4fl..4fl+3 (bf16 pairs),
// quarter q processes edge i+q.
__global__ void gather1_kernel(const __hip_bfloat16* __restrict__ h1,
                               const int2* __restrict__ rowrange,
                               const int2* __restrict__ rec,
                               float* __restrict__ agg, int n_nodes) {
    int n = blockIdx.x * 4 + (threadIdx.x >> 6);
    if (n >= n_nodes) return;
    int lane = threadIdx.x & 63;
    int q = lane >> 4;
    int fl = lane & 15;
    const uint2* h1v = reinterpret_cast<const uint2*>(h1);
    int2 rr = rowrange[n];
    int i = rr.x, end = rr.y;
    float a0 = 0.f, a1 = 0.f, a2 = 0.f, a3 = 0.f;
    for (; i + 7 < end; i += 8) {           // 8 edges: 2 rec loads + 2 gathers
        int2 r0 = rec[i + q];
        int2 r1 = rec[i + 4 + q];
        uint2 v0 = h1v[(size_t)(r0.x & 0xFFFFF) * 16 + fl];
        uint2 v1 = h1v[(size_t)(r1.x & 0xFFFFF) * 16 + fl];
        float w0 = __int_as_float(r0.y), w1 = __int_as_float(r1.y);
        a0 += __uint_as_float(v0.x << 16) * w0;
        a1 += __uint_as_float(v0.x & 0xFFFF0000u) * w0;
        a2 += __uint_as_float(v0.y << 16) * w0;
        a3 += __uint_as_float(v0.y & 0xFFFF0000u) * w0;
        a0 += __uint_as_float(v1.x << 16) * w1;
        a1 += __uint_as_float(v1.x & 0xFFFF0000u) * w1;
        a2 += __uint_as_float(v1.y << 16) * w1;
        a3 += __uint_as_float(v1.y & 0xFFFF0000u) * w1;
    }
    if (i + 3 < end) {                      // 4 edges
        int2 r = rec[i + q];
        uint2 v = h1v[(size_t)(r.x & 0xFFFFF) * 16 + fl];
        float w = __int_as_float(r.y);
        a0 += __uint_as_float(v.x << 16) * w;
        a1 += __uint_as_float(v.x & 0xFFFF0000u) * w;
        a2 += __uint_as_float(v.y << 16) * w;
        a3 += __uint_as_float(v.y & 0xFFFF0000u) * w;
        i += 4;
    }
    if (i + q < end) {                      // ragged tail (quarter-masked)
        int2 r = rec[i + q];
        uint2 v = h1v[(size_t)(r.x & 0xFFFFF) * 16 + fl];
        float w = __int_as_float(r.y);
        a0 += __uint_as_float(v.x << 16) * w;
        a1 += __uint_as_float(v.x & 0xFFFF0000u) * w;
        a2 += __uint_as_float(v.y << 16) * w;
        a3 += __uint_as_float(v.y & 0xFFFF0000u) * w;
    }
    a0 += __shfl_xor(a0, 16, 64);  a0 += __shfl_xor(a0, 32, 64);
    a1 += __shfl_xor(a1, 16, 64);  a1 += __shfl_xor(a1, 32, 64);
    a2 += __shfl_xor(a2, 16, 64);  a2 += __shfl_xor(a2, 32, 64);
    a3 += __shfl_xor(a3, 16, 64);  a3 += __shfl_xor(a3, 32, 64);
    if (q == 0) {
        float4 st = make_float4(fmaxf(a0, 0.f), fmaxf(a1, 0.f),
                                fmaxf(a2, 0.f), fmaxf(a3, 0.f));   // fused relu
        *reinterpret_cast<float4*>(&agg[(size_t)n * 64 + fl * 4]) = st;
    }
}

// ---------------- gather2: wave per node, 4 edges per gather instruction ----------------
__global__ void gather2_kernel(const float* __restrict__ h2,
                               const int2* __restrict__ rowrange,
                               const int2* __restrict__ rec,
                               float* __restrict__ out, int n_nodes) {
    int n = blockIdx.x * 4 + (threadIdx.x >> 6);
    if (n >= n_nodes) return;
    int lane = threadIdx.x & 63;
    int q = lane >> 4;
    int fl = lane & 15;
    int2 rr = rowrange[n];
    int i = rr.x, end = rr.y;
    float a0 = 0.f, a1 = 0.f;
    for (; i + 7 < end; i += 8) {
        int2 r0 = rec[i + q];
        int2 r1 = rec[i + 4 + q];
        float v0 = h2[(size_t)(r0.x & 0xFFFFF) * 16 + fl];
        float v1 = h2[(size_t)(r1.x & 0xFFFFF) * 16 + fl];
        a0 += v0 * __int_as_float(r0.y);
        a1 += v1 * __int_as_float(r1.y);
    }
    if (i + 3 < end) {
        int2 r = rec[i + q];
        a0 += h2[(size_t)(r.x & 0xFFFFF) * 16 + fl] * __int_as_float(r.y);
        i += 4;
    }
    if (i + q < end) {
        int2 r = rec[i + q];
        a1 += h2[(size_t)(r.x & 0xFFFFF) * 16 + fl] * __int_as_float(r.y);
    }
    float a = a0 + a1;
    a += __shfl_xor(a, 16, 64);
    a += __shfl_xor(a, 32, 64);
    if (q == 0) out[(size_t)n * 16 + fl] = a;
}

// ---------------- launch ----------------

extern "C" void kernel_launch(void* const* d_in, const int* in_sizes, int n_in,
                              void* d_out, int out_size, void* d_ws, size_t ws_size,
                              hipStream_t stream) {
    const float* x   = (const float*)d_in[0];
    const int*   ei1 = (const int*)d_in[1];
    const int*   ei2 = (const int*)d_in[2];
    const float* ew1 = (const float*)d_in[3];
    const float* ew2 = (const float*)d_in[4];
    const float* W1  = (const float*)d_in[5];
    const float* W2  = (const float*)d_in[6];

    const int n_nodes = in_sizes[0] / 128;          // 100000
    const int n_edges = in_sizes[1] / 2;            // 1600000
    const int nb   = (n_nodes + 255) >> 8;          // 391 buckets
    const int nblk = (n_edges + EPB - 1) / EPB;     // 391 binning blocks

    // ws layout (4-byte units); total ~77.6 MB
    __hip_bfloat16* h1 = (__hip_bfloat16*)d_ws;          // N*64 bf16
    float* agg1   = (float*)d_ws + (size_t)n_nodes * 32; // N*64
    float* h2     = agg1 + (size_t)n_nodes * 64;         // N*16
    int2*  recbuf = (int2*)(h2 + (size_t)n_nodes * 16);  // nb*BSTRIDE int2 (bucket regions)
    int2*  rec2   = recbuf + (size_t)nb * BSTRIDE;       // nb*BSTRIDE int2 (node-sorted)
    int*   cursor = (int*)(rec2 + (size_t)nb * BSTRIDE); // nb
    int2*  rowrng = (int2*)(cursor + nb);                // N int2
    float* out    = (float*)d_out;

    const int g1_blocks = 1024;                          // 4096 waves, grid-stride

    // ---- layer 1 ----
    gemm1_kernel<<<g1_blocks, 256, 0, stream>>>(x, W1, h1, n_nodes, g1_blocks * 4);
    init_cursor_kernel<<<1, 512, 0, stream>>>(cursor, nb);
    bin_scatter_kernel<<<nblk, 256, 0, stream>>>(ei1, ew1, cursor, recbuf, n_edges, nb);
    bucket_sort_kernel<<<nb, 256, 0, stream>>>(recbuf, cursor, rec2, rowrng, n_nodes, nb);
    gather1_kernel<<<(n_nodes + 3) / 4, 256, 0, stream>>>(h1, rowrng, rec2, agg1, n_nodes);

    // ---- layer 2 ----
    gemm2_kernel<<<g1_blocks, 256, 0, stream>>>(agg1, W2, h2, n_nodes, g1_blocks * 4);
    init_cursor_kernel<<<1, 512, 0, stream>>>(cursor, nb);
    bin_scatter_kernel<<<nblk, 256, 0, stream>>>(ei2, ew2, cursor, recbuf, n_edges, nb);
    bucket_sort_kernel<<<nb, 256, 0, stream>>>(recbuf, cursor, rec2, rowrng, n_nodes, nb);
    gather2_kernel<<<(n_nodes + 3) / 4, 256, 0, stream>>>(h2, rowrng, rec2, out, n_nodes);
}

// Round 12
// 384.685 us; speedup vs baseline: 2.3892x; 1.3426x over previous
//
#include <hip/hip_runtime.h>
#include <hip/hip_bf16.h>

// GCN 2-layer, fp32 I/O. 7 launches:
//   gemm1 -> init_cursors -> bin_scatter1 -> sortgather1 -> gemm2 -> bin_scatter2 -> sortgather2
// Edges bucket-sorted by dst>>8 into fixed 5120-rec regions (16-sigma), then each
// sortgather block counting-sorts its bucket in LDS (by dst&255) and gathers from it.
// h1 bf16 (halves gather BW). Record int2: .x = src | (dst&255)<<20, .y = w bits.

#define EPB 4096      // edges per binning block
#define NBMAX 512     // max buckets (N <= 131072)
#define BSTRIDE 5120  // fixed records per bucket region (avg 4096 + 16 sigma)

// ---------------- gemm1: [N,128] @ [128,64] -> bf16 [N,64] ----------------
// 256 threads, tile 256n x 64f, thread 8n x 8f. k-major LDS with PERMUTED rows:
// LDS row r holds actual k = (r&7)*4 + (r>>3); staging component c -> row kq+8c gives
// bank (4*kq+n)%32 = 2 lanes/bank (free). Bs staged through the same permutation.
__global__ __launch_bounds__(256) void gemm1_kernel(const float* __restrict__ x,
                                                    const float* __restrict__ W1,
                                                    __hip_bfloat16* __restrict__ h1,
                                                    int n_nodes) {
    __shared__ float As[32][260];   // 33.3 KB (256n, pad 260: 260%32==4 keeps 2-way)
    __shared__ float Bs[32][64];    // 8 KB
    int tid = threadIdx.x;
    int node0 = blockIdx.x * 256;
    int n8 = (tid & 31) * 8;
    int f8 = (tid >> 5) * 8;
    float acc[8][8];
#pragma unroll
    for (int i = 0; i < 8; ++i)
#pragma unroll
        for (int j = 0; j < 8; ++j) acc[i][j] = 0.f;

    const float4* x4 = reinterpret_cast<const float4*>(x);
    const float4* W4 = reinterpret_cast<const float4*>(W1);

    for (int s = 0; s < 4; ++s) {
        // stage As: 2048 float4 (8/thread); component c -> row kq+8c, col n
#pragma unroll
        for (int j = 0; j < 8; ++j) {
            int idx = tid + j * 256;
            int n = idx >> 3;
            int kq = idx & 7;
            float4 v = make_float4(0.f, 0.f, 0.f, 0.f);
            if (node0 + n < n_nodes) v = x4[(size_t)(node0 + n) * 32 + s * 8 + kq];
            As[kq +  0][n] = v.x;
            As[kq +  8][n] = v.y;
            As[kq + 16][n] = v.z;
            As[kq + 24][n] = v.w;
        }
        // stage Bs with matching permutation: row r <- W row s*32 + (r&7)*4 + (r>>3)
#pragma unroll
        for (int j = 0; j < 2; ++j) {
            int idx = tid + j * 256;
            int r = idx >> 4;
            int fq = idx & 15;
            int krow = s * 32 + (r & 7) * 4 + (r >> 3);
            *reinterpret_cast<float4*>(&Bs[r][fq * 4]) = W4[(size_t)krow * 16 + fq];
        }
        __syncthreads();
#pragma unroll
        for (int kk = 0; kk < 32; ++kk) {
            float4 a0 = *reinterpret_cast<const float4*>(&As[kk][n8]);
            float4 a1 = *reinterpret_cast<const float4*>(&As[kk][n8 + 4]);
            float4 b0 = *reinterpret_cast<const float4*>(&Bs[kk][f8]);
            float4 b1 = *reinterpret_cast<const float4*>(&Bs[kk][f8 + 4]);
            float av[8] = {a0.x, a0.y, a0.z, a0.w, a1.x, a1.y, a1.z, a1.w};
            float bv[8] = {b0.x, b0.y, b0.z, b0.w, b1.x, b1.y, b1.z, b1.w};
#pragma unroll
            for (int i = 0; i < 8; ++i)
#pragma unroll
                for (int j = 0; j < 8; ++j) acc[i][j] += av[i] * bv[j];
        }
        __syncthreads();
    }
#pragma unroll
    for (int i = 0; i < 8; ++i) {
        int n = node0 + n8 + i;
        if (n < n_nodes) {
            __hip_bfloat16 tmp[8];
#pragma unroll
            for (int j = 0; j < 8; ++j) tmp[j] = __float2bfloat16(acc[i][j]);
            *reinterpret_cast<uint4*>(&h1[(size_t)n * 64 + f8]) =
                *reinterpret_cast<const uint4*>(tmp);
        }
    }
}

// ---------------- gemm2: [N,64] @ [64,16] -> fp32 [N,16] ----------------
// 256 threads, tile 128n x 16f, thread 2n x 4f; same permuted-k staging.
__global__ __launch_bounds__(256) void gemm2_kernel(const float* __restrict__ agg1,
                                                    const float* __restrict__ W2,
                                                    float* __restrict__ h2, int n_nodes) {
    __shared__ float As[32][132];
    __shared__ float Bs[32][16];
    int tid = threadIdx.x;
    int node0 = blockIdx.x * 128;
    int n2 = (tid & 63) * 2;
    int f4 = (tid >> 6) * 4;
    float acc[2][4];
#pragma unroll
    for (int i = 0; i < 2; ++i)
#pragma unroll
        for (int j = 0; j < 4; ++j) acc[i][j] = 0.f;

    const float4* a4 = reinterpret_cast<const float4*>(agg1);
    const float4* W4 = reinterpret_cast<const float4*>(W2);

    for (int s = 0; s < 2; ++s) {
#pragma unroll
        for (int j = 0; j < 4; ++j) {
            int idx = tid + j * 256;
            int n = idx >> 3;
            int kq = idx & 7;
            float4 v = make_float4(0.f, 0.f, 0.f, 0.f);
            if (node0 + n < n_nodes) v = a4[(size_t)(node0 + n) * 16 + s * 8 + kq];
            As[kq +  0][n] = v.x;
            As[kq +  8][n] = v.y;
            As[kq + 16][n] = v.z;
            As[kq + 24][n] = v.w;
        }
        if (tid < 128) {
            int r = tid >> 2, fq = tid & 3;
            int krow = s * 32 + (r & 7) * 4 + (r >> 3);
            *reinterpret_cast<float4*>(&Bs[r][fq * 4]) = W4[(size_t)krow * 4 + fq];
        }
        __syncthreads();
#pragma unroll
        for (int kk = 0; kk < 32; ++kk) {
            float2 a = *reinterpret_cast<const float2*>(&As[kk][n2]);
            float4 b = *reinterpret_cast<const float4*>(&Bs[kk][f4]);
            float av[2] = {a.x, a.y};
            float bv[4] = {b.x, b.y, b.z, b.w};
#pragma unroll
            for (int i = 0; i < 2; ++i)
#pragma unroll
                for (int j = 0; j < 4; ++j) acc[i][j] += av[i] * bv[j];
        }
        __syncthreads();
    }
#pragma unroll
    for (int i = 0; i < 2; ++i) {
        int n = node0 + n2 + i;
        if (n < n_nodes)
            *reinterpret_cast<float4*>(h2 + (size_t)n * 16 + f4) =
                make_float4(acc[i][0], acc[i][1], acc[i][2], acc[i][3]);
    }
}

// ---------------- init: both layers' cursors ----------------
__global__ __launch_bounds__(512) void init_cursors_kernel(int* __restrict__ c1,
                                                           int* __restrict__ c2, int nb) {
    int i = threadIdx.x;
    if (i < nb) { c1[i] = i * BSTRIDE; c2[i] = i * BSTRIDE; }
}

// ---------------- bin_scatter: LDS counting sort by dst>>8 into fixed regions ----------------
__global__ void bin_scatter_kernel(const int* __restrict__ ei, const float* __restrict__ ew,
                                   int* __restrict__ cursor, int2* __restrict__ rec_out,
                                   int n_edges, int nb) {
    __shared__ int2 srec[EPB];               // 32 KB
    __shared__ unsigned short sbkt[EPB];     // 8 KB
    __shared__ int hist[NBMAX], loff[NBMAX], cur[NBMAX], gbase[NBMAX];
    __shared__ int p[256];
    int tid = threadIdx.x, blk = blockIdx.x;
    int e0 = blk * EPB;
    int cnt = min(EPB, n_edges - e0);
    for (int i = tid; i < nb; i += 256) hist[i] = 0;
    __syncthreads();
    int dcache[EPB / 256];                   // dst cached in regs between passes
#pragma unroll
    for (int j = 0; j < EPB / 256; ++j) {
        int e = e0 + tid + j * 256;
        int d = (e < n_edges) ? ei[n_edges + e] : -1;
        dcache[j] = d;
        if (d >= 0) atomicAdd(&hist[d >> 8], 1);
    }
    __syncthreads();
    // exclusive scan of hist -> loff (2 buckets/thread + Hillis-Steele over partials)
    int b0 = tid * 2;
    int c0 = (b0 < nb) ? hist[b0] : 0;
    int c1 = (b0 + 1 < nb) ? hist[b0 + 1] : 0;
    p[tid] = c0 + c1;
    __syncthreads();
    for (int off = 1; off < 256; off <<= 1) {
        int t = (tid >= off) ? p[tid - off] : 0;
        __syncthreads();
        p[tid] += t;
        __syncthreads();
    }
    int base = (tid > 0) ? p[tid - 1] : 0;
    __syncthreads();
    if (b0 < nb)     { loff[b0] = base;          cur[b0] = base; }
    if (b0 + 1 < nb) { loff[b0 + 1] = base + c0; cur[b0 + 1] = base + c0; }
    if (b0 < nb)     gbase[b0]     = (c0 > 0) ? atomicAdd(&cursor[b0], c0) : 0;
    if (b0 + 1 < nb) gbase[b0 + 1] = (c1 > 0) ? atomicAdd(&cursor[b0 + 1], c1) : 0;
    __syncthreads();
    // rank + stage
#pragma unroll
    for (int j = 0; j < EPB / 256; ++j) {
        int e = e0 + tid + j * 256;
        int d = dcache[j];
        if (d >= 0) {
            int b = d >> 8;
            int r = atomicAdd(&cur[b], 1);
            srec[r] = make_int2(ei[e] | ((d & 255) << 20), __float_as_int(ew[e]));
            sbkt[r] = (unsigned short)b;
        }
    }
    __syncthreads();
    // coalesced run writes
    for (int i = tid; i < cnt; i += 256) {
        int b = sbkt[i];
        rec_out[gbase[b] + (i - loff[b])] = srec[i];
    }
}

// ---------------- sortgather1: LDS sort by dst&255 + gather (F=64 bf16) ----------------
__global__ __launch_bounds__(512) void sortgather1_kernel(
        const __hip_bfloat16* __restrict__ h1, const int* __restrict__ cursor,
        const int2* __restrict__ rec_in, float* __restrict__ agg, int n_nodes) {
    __shared__ int2 srec[BSTRIDE];           // 40 KB
    __shared__ int cur[256];
    __shared__ int rstart[257];
    int tid = threadIdx.x, b = blockIdx.x;
    int start = b * BSTRIDE;
    int cnt = min(cursor[b] - start, BSTRIDE);
    if (tid < 256) cur[tid] = 0;
    __syncthreads();
    int2 v[10];                              // records cached in regs (<=5120/512)
#pragma unroll
    for (int j = 0; j < 10; ++j) {
        int i = tid + j * 512;
        if (i < cnt) {
            v[j] = rec_in[start + i];
            atomicAdd(&cur[(v[j].x >> 20) & 255], 1);
        }
    }
    __syncthreads();
    int hv = (tid < 256) ? cur[tid] : 0;
    if (tid < 256) rstart[tid] = hv;
    __syncthreads();
    for (int off = 1; off < 256; off <<= 1) {
        int t = (tid >= off && tid < 256) ? rstart[tid - off] : 0;
        __syncthreads();
        if (tid < 256) rstart[tid] += t;
        __syncthreads();
    }
    if (tid < 256) {
        int excl = rstart[tid] - hv;         // exclusive scan
        cur[tid] = excl;
        rstart[tid] = excl;
    }
    if (tid == 0) rstart[256] = cnt;
    __syncthreads();
    // stage sorted
#pragma unroll
    for (int j = 0; j < 10; ++j) {
        int i = tid + j * 512;
        if (i < cnt) {
            int rk = atomicAdd(&cur[(v[j].x >> 20) & 255], 1);
            if (rk < BSTRIDE) srec[rk] = v[j];
        }
    }
    __syncthreads();
    // gather: wave owns 32 nodes; lane = (quarter q, uint2-feat fl); 4 edges/instr
    int wave = tid >> 6, lane = tid & 63;
    int q = lane >> 4, fl = lane & 15;
    const uint2* h1v = reinterpret_cast<const uint2*>(h1);
    int node0 = b << 8;
    for (int t = 0; t < 32; ++t) {
        int nl = wave * 32 + t;
        int n = node0 + nl;
        if (n >= n_nodes) break;
        int i = rstart[nl], end = rstart[nl + 1];
        float a0 = 0.f, a1 = 0.f, a2 = 0.f, a3 = 0.f;
        for (; i + 7 < end; i += 8) {
            int2 r0 = srec[i + q];
            int2 r1 = srec[i + 4 + q];
            uint2 v0 = h1v[(size_t)(r0.x & 0xFFFFF) * 16 + fl];
            uint2 v1 = h1v[(size_t)(r1.x & 0xFFFFF) * 16 + fl];
            float w0 = __int_as_float(r0.y), w1 = __int_as_float(r1.y);
            a0 += __uint_as_float(v0.x << 16) * w0;
            a1 += __uint_as_float(v0.x & 0xFFFF0000u) * w0;
            a2 += __uint_as_float(v0.y << 16) * w0;
            a3 += __uint_as_float(v0.y & 0xFFFF0000u) * w0;
            a0 += __uint_as_float(v1.x << 16) * w1;
            a1 += __uint_as_float(v1.x & 0xFFFF0000u) * w1;
            a2 += __uint_as_float(v1.y << 16) * w1;
            a3 += __uint_as_float(v1.y & 0xFFFF0000u) * w1;
        }
        if (i + 3 < end) {
            int2 r = srec[i + q];
            uint2 vv = h1v[(size_t)(r.x & 0xFFFFF) * 16 + fl];
            float w = __int_as_float(r.y);
            a0 += __uint_as_float(vv.x << 16) * w;
            a1 += __uint_as_float(vv.x & 0xFFFF0000u) * w;
            a2 += __uint_as_float(vv.y << 16) * w;
            a3 += __uint_as_float(vv.y & 0xFFFF0000u) * w;
            i += 4;
        }
        if (i + q < end) {
            int2 r = srec[i + q];
            uint2 vv = h1v[(size_t)(r.x & 0xFFFFF) * 16 + fl];
            float w = __int_as_float(r.y);
            a0 += __uint_as_float(vv.x << 16) * w;
            a1 += __uint_as_float(vv.x & 0xFFFF0000u) * w;
            a2 += __uint_as_float(vv.y << 16) * w;
            a3 += __uint_as_float(vv.y & 0xFFFF0000u) * w;
        }
        a0 += __shfl_xor(a0, 16, 64);  a0 += __shfl_xor(a0, 32, 64);
        a1 += __shfl_xor(a1, 16, 64);  a1 += __shfl_xor(a1, 32, 64);
        a2 += __shfl_xor(a2, 16, 64);  a2 += __shfl_xor(a2, 32, 64);
        a3 += __shfl_xor(a3, 16, 64);  a3 += __shfl_xor(a3, 32, 64);
        if (q == 0) {
            float4 st = make_float4(fmaxf(a0, 0.f), fmaxf(a1, 0.f),
                                    fmaxf(a2, 0.f), fmaxf(a3, 0.f));   // fused relu
            *reinterpret_cast<float4*>(&agg[(size_t)n * 64 + fl * 4]) = st;
        }
    }
}

// ---------------- sortgather2: LDS sort + gather (F=16 fp32) ----------------
__global__ __launch_bounds__(512) void sortgather2_kernel(
        const float* __restrict__ h2, const int* __restrict__ cursor,
        const int2* __restrict__ rec_in, float* __restrict__ out, int n_nodes) {
    __shared__ int2 srec[BSTRIDE];           // 40 KB
    __shared__ int cur[256];
    __shared__ int rstart[257];
    int tid = threadIdx.x, b = blockIdx.x;
    int start = b * BSTRIDE;
    int cnt = min(cursor[b] - start, BSTRIDE);
    if (tid < 256) cur[tid] = 0;
    __syncthreads();
    int2 v[10];
#pragma unroll
    for (int j = 0; j < 10; ++j) {
        int i = tid + j * 512;
        if (i < cnt) {
            v[j] = rec_in[start + i];
            atomicAdd(&cur[(v[j].x >> 20) & 255], 1);
        }
    }
    __syncthreads();
    int hv = (tid < 256) ? cur[tid] : 0;
    if (tid < 256) rstart[tid] = hv;
    __syncthreads();
    for (int off = 1; off < 256; off <<= 1) {
        int t = (tid >= off && tid < 256) ? rstart[tid - off] : 0;
        __syncthreads();
        if (tid < 256) rstart[tid] += t;
        __syncthreads();
    }
    if (tid < 256) {
        int excl = rstart[tid] - hv;
        cur[tid] = excl;
        rstart[tid] = excl;
    }
    if (tid == 0) rstart[256] = cnt;
    __syncthreads();
#pragma unroll
    for (int j = 0; j < 10; ++j) {
        int i = tid + j * 512;
        if (i < cnt) {
            int rk = atomicAdd(&cur[(v[j].x >> 20) & 255], 1);
            if (rk < BSTRIDE) srec[rk] = v[j];
        }
    }
    __syncthreads();
    int wave = tid >> 6, lane = tid & 63;
    int q = lane >> 4, fl = lane & 15;
    int node0 = b << 8;
    for (int t = 0; t < 32; ++t) {
        int nl = wave * 32 + t;
        int n = node0 + nl;
        if (n >= n_nodes) break;
        int i = rstart[nl], end = rstart[nl + 1];
        float a0 = 0.f, a1 = 0.f;
        for (; i + 7 < end; i += 8) {
            int2 r0 = srec[i + q];
            int2 r1 = srec[i + 4 + q];
            a0 += h2[(size_t)(r0.x & 0xFFFFF) * 16 + fl] * __int_as_float(r0.y);
            a1 += h2[(size_t)(r1.x & 0xFFFFF) * 16 + fl] * __int_as_float(r1.y);
        }
        if (i + 3 < end) {
            int2 r = srec[i + q];
            a0 += h2[(size_t)(r.x & 0xFFFFF) * 16 + fl] * __int_as_float(r.y);
            i += 4;
        }
        if (i + q < end) {
            int2 r = srec[i + q];
            a1 += h2[(size_t)(r.x & 0xFFFFF) * 16 + fl] * __int_as_float(r.y);
        }
        float a = a0 + a1;
        a += __shfl_xor(a, 16, 64);
        a += __shfl_xor(a, 32, 64);
        if (q == 0) out[(size_t)n * 16 + fl] = a;
    }
}

// ---------------- launch ----------------

extern "C" void kernel_launch(void* const* d_in, const int* in_sizes, int n_in,
                              void* d_out, int out_size, void* d_ws, size_t ws_size,
                              hipStream_t stream) {
    const float* x   = (const float*)d_in[0];
    const int*   ei1 = (const int*)d_in[1];
    const int*   ei2 = (const int*)d_in[2];
    const float* ew1 = (const float*)d_in[3];
    const float* ew2 = (const float*)d_in[4];
    const float* W1  = (const float*)d_in[5];
    const float* W2  = (const float*)d_in[6];

    const int n_nodes = in_sizes[0] / 128;          // 100000
    const int n_edges = in_sizes[1] / 2;            // 1600000
    const int nb   = (n_nodes + 255) >> 8;          // 391 buckets
    const int nblk = (n_edges + EPB - 1) / EPB;     // 391 binning blocks

    // ws layout (4-byte units); ~61 MB
    __hip_bfloat16* h1 = (__hip_bfloat16*)d_ws;          // N*64 bf16
    float* agg1   = (float*)d_ws + (size_t)n_nodes * 32; // N*64
    float* h2     = agg1 + (size_t)n_nodes * 64;         // N*16
    int2*  recbuf = (int2*)(h2 + (size_t)n_nodes * 16);  // nb*BSTRIDE int2
    int*   cur1   = (int*)(recbuf + (size_t)nb * BSTRIDE);
    int*   cur2   = cur1 + nb;
    float* out    = (float*)d_out;

    init_cursors_kernel<<<1, 512, 0, stream>>>(cur1, cur2, nb);

    // ---- layer 1 ----
    gemm1_kernel<<<(n_nodes + 255) / 256, 256, 0, stream>>>(x, W1, h1, n_nodes);
    bin_scatter_kernel<<<nblk, 256, 0, stream>>>(ei1, ew1, cur1, recbuf, n_edges, nb);
    sortgather1_kernel<<<nb, 512, 0, stream>>>(h1, cur1, recbuf, agg1, n_nodes);

    // ---- layer 2 ----
    gemm2_kernel<<<(n_nodes + 127) / 128, 256, 0, stream>>>(agg1, W2, h2, n_nodes);
    bin_scatter_kernel<<<nblk, 256, 0, stream>>>(ei2, ew2, cur2, recbuf, n_edges, nb);
    sortgather2_kernel<<<nb, 512, 0, stream>>>(h2, cur2, recbuf, out, n_nodes);
}